// Round 10
// baseline (242.363 us; speedup 1.0000x reference)
//
#include <hip/hip_runtime.h>

// Shapes (fixed)
#define SEQ   2048
#define NB    2
#define NHQ   32
#define NHKV  8
#define HD    128
#define QTILE 128      // q rows per block (4 waves x 32 q)
#define QW    32
#define KVB   32
#define NT    (SEQ / KVB)    // 64 kv tiles
#define SCALE 0.08838834764831845f
#define QSCALE (0.08838834764831845f * 1.4426950408889634f)   // fold log2(e): use exp2
#define THRL2 11.5f

#define QSTRIDE (NB * NHQ * HD)    // 8192
#define KSTRIDE (NB * NHKV * HD)   // 2048

typedef float f32x4  __attribute__((ext_vector_type(4)));
typedef float f32x16 __attribute__((ext_vector_type(16)));
typedef __bf16 bf16x8 __attribute__((ext_vector_type(8)));
typedef unsigned short ushort8 __attribute__((ext_vector_type(8)));
typedef unsigned int u32;
typedef unsigned int u32x2 __attribute__((ext_vector_type(2)));
typedef unsigned int u32x4 __attribute__((ext_vector_type(4)));

__device__ __forceinline__ unsigned short f2bf(float f) {
    union { float f; unsigned u; } c; c.f = f;
    return (unsigned short)((c.u + 0x7fffu + ((c.u >> 16) & 1u)) >> 16);
}

__device__ __forceinline__ void gload_lds16(const unsigned short* g, unsigned short* l) {
    __builtin_amdgcn_global_load_lds((const __attribute__((address_space(1))) u32*)g,
                                     (__attribute__((address_space(3))) u32*)l, 16, 0, 0);
}

__device__ __forceinline__ float ex2(float x) {
#if __has_builtin(__builtin_amdgcn_exp2f)
    return __builtin_amdgcn_exp2f(x);
#else
    return exp2f(x);
#endif
}

__device__ __forceinline__ u32 cvtpk(float lo, float hi) {
    u32 r;
    asm("v_cvt_pk_bf16_f32 %0, %1, %2" : "=v"(r) : "v"(lo), "v"(hi));
    return r;
}

// v_permlane32_swap_b32 a, b : swaps a's UPPER 32 lanes with b's LOWER 32 lanes
__device__ __forceinline__ void pl32swap(u32& a, u32& b) {
#if __has_builtin(__builtin_amdgcn_permlane32_swap)
    u32x2 r = __builtin_amdgcn_permlane32_swap(a, b, false, false);
    a = r.x; b = r.y;
#else
    asm("v_permlane32_swap_b32 %0, %1" : "+v"(a), "+v"(b));
#endif
}

// Pack 8 f32 P values (C-layout rows r=B..B+7) into one PV B-fragment:
// pa elem j = P[8h + j] of the 16-kv slice. Verified R4.
template <int B>
__device__ __forceinline__ bf16x8 make_pa(const f32x16 p) {
    u32 w0 = cvtpk(p[B + 0], p[B + 1]);
    u32 w2 = cvtpk(p[B + 4], p[B + 5]);
    pl32swap(w0, w2);
    u32 w1 = cvtpk(p[B + 2], p[B + 3]);
    u32 w3 = cvtpk(p[B + 6], p[B + 7]);
    pl32swap(w1, w3);
    u32x4 v = {w0, w1, w2, w3};
    return __builtin_bit_cast(bf16x8, v);
}

// ---------------- pre-pass 1: K -> bf16, XOR-swizzled 16B chunks (3-bit, 256B rows) ----------------
__global__ __launch_bounds__(256) void conv_k(const float* __restrict__ K,
                                              unsigned short* __restrict__ Kws) {
    int idx = blockIdx.x * 256 + threadIdx.x;
    int c  = idx & 15;
    int s  = (idx >> 4) & 2047;
    int bh = idx >> 15;
    int cs = c ^ (s & 7);
    const float* src = K + ((size_t)s * 16 + bh) * 128 + cs * 8;
    float4 f0 = *(const float4*)src;
    float4 f1 = *(const float4*)(src + 4);
    ushort8 u;
    u[0] = f2bf(f0.x); u[1] = f2bf(f0.y); u[2] = f2bf(f0.z); u[3] = f2bf(f0.w);
    u[4] = f2bf(f1.x); u[5] = f2bf(f1.y); u[6] = f2bf(f1.z); u[7] = f2bf(f1.w);
    *(ushort8*)&Kws[((size_t)bh * 2048 + s) * 128 + c * 8] = u;
}

// ------- pre-pass 2: V -> bf16 in PV-fragment order: Vt2[bh][tile][ks][db][lane][j] -------
// value = V[seq = 32*tile + 16ks + 8*(lane>>5) + j][bh][d = 32db + (lane&31)]
__global__ __launch_bounds__(256) void conv_v(const float* __restrict__ V,
                                              unsigned short* __restrict__ Vt2) {
    __shared__ float tile[64][129];
    int t64 = blockIdx.x & 31;
    int bh  = blockIdx.x >> 5;
    int kv0 = t64 * 64;
#pragma unroll
    for (int i = 0; i < 8; ++i) {
        int f4 = i * 256 + threadIdx.x;
        int kv = f4 >> 5, d4 = (f4 & 31) * 4;
        float4 v = *(const float4*)(V + ((size_t)(kv0 + kv) * 16 + bh) * 128 + d4);
        tile[kv][d4] = v.x; tile[kv][d4 + 1] = v.y;
        tile[kv][d4 + 2] = v.z; tile[kv][d4 + 3] = v.w;
    }
    __syncthreads();
#pragma unroll
    for (int i = 0; i < 4; ++i) {
        int lin = i * 256 + threadIdx.x;   // 0..1023 = tt(2) x ks(2) x db(4) x lane(64)
        int l  = lin & 63;
        int db = (lin >> 6) & 3;
        int ks = (lin >> 8) & 1;
        int tt = lin >> 9;
        int h = l >> 5, q31 = l & 31;
        ushort8 u;
#pragma unroll
        for (int j = 0; j < 8; ++j)
            u[j] = f2bf(tile[tt * 32 + ks * 16 + h * 8 + j][db * 32 + q31]);
        size_t off = ((((size_t)bh * 64 + (t64 * 2 + tt)) * 2 + ks) * 4 + db) * 512 + l * 8;
        *(ushort8*)&Vt2[off] = u;
    }
}

// -------- main kernel: 4 waves x 32q, KVB=32; K via LDS tri-buffer, V direct L2->regs --------
// K region: [0, 24576) = 3 x 8 KB ; epilogue reuses [0, 34816): 4 waves x 32x68 f32
__global__ __launch_bounds__(256, 3)
void attn_fwd9(const float* __restrict__ Q, const unsigned short* __restrict__ Kws,
               const unsigned short* __restrict__ Vt2, float* __restrict__ O) {
    __shared__ __align__(16) unsigned char smemc[34816];

    const int tid  = threadIdx.x;
    const int w    = tid >> 6;     // 0..3
    const int lane = tid & 63;
    const int q31  = lane & 31;
    const int h    = lane >> 5;

    // XCD-locality decode: hkv = bid&7
    const int bid   = blockIdx.x;
    const int hkv   = bid & 7;
    const int rest  = bid >> 3;
    const int g     = rest & 3;
    const int b     = (rest >> 2) & 1;
    const int qtile = rest >> 3;          // 0..15
    const int hq    = hkv * 4 + g;

    const int qrow = qtile * QTILE + w * QW + q31;

    // ---- Q B-fragments: qf[s] elem j = Q[qrow][16s+8h+j] * QSCALE ----
    bf16x8 qf[8];
    {
        const float* qp = Q + (size_t)qrow * QSTRIDE + b * (NHQ * HD) + hq * HD;
#pragma unroll
        for (int s = 0; s < 8; ++s) {
            const float* p = qp + (2 * s + h) * 8;
            float4 f0 = *(const float4*)(p);
            float4 f1 = *(const float4*)(p + 4);
            ushort8 u;
            u[0] = f2bf(f0.x * QSCALE); u[1] = f2bf(f0.y * QSCALE);
            u[2] = f2bf(f0.z * QSCALE); u[3] = f2bf(f0.w * QSCALE);
            u[4] = f2bf(f1.x * QSCALE); u[5] = f2bf(f1.y * QSCALE);
            u[6] = f2bf(f1.z * QSCALE); u[7] = f2bf(f1.w * QSCALE);
            qf[s] = __builtin_bit_cast(bf16x8, u);
        }
    }

    // per-lane K LDS byte addresses (buffer-0-relative)
    u32 kad[8];
#pragma unroll
    for (int s = 0; s < 8; ++s)
        kad[s] = q31 * 256 + (((2 * s + h) ^ (q31 & 7)) << 4);

    f32x16 acc[4];
#pragma unroll
    for (int db = 0; db < 4; ++db) acc[db] = (f32x16)0.f;
    float mr = -3e38f, lsum = 0.f;

    const unsigned short* kbh = Kws + (size_t)(b * 8 + hkv) * 2048 * 128;
    const unsigned short* vbh = Vt2 + (size_t)(b * 8 + hkv) * 2048 * 128;

    // per wave per STAGE_K: 2 chunk loads (1 KB each)
#define STAGE_K(sofb, tt) do {                                                         \
        const int kv0s = (tt) * KVB;                                                   \
        _Pragma("unroll")                                                              \
        for (int i_ = 0; i_ < 2; ++i_) {                                               \
            const int c_ = w * 2 + i_;                                                 \
            gload_lds16(kbh + (size_t)(kv0s + c_ * 4 + (lane >> 4)) * 128 + (lane & 15) * 8, \
                        (unsigned short*)(smemc + (sofb) + c_ * 1024));                \
        }                                                                              \
    } while (0)

    // prologue: stage K tiles 0,1 ; wait K0 (leave K1 in flight)
    STAGE_K(0, 0);
    STAGE_K(8192, 1);
    asm volatile("s_waitcnt vmcnt(2)" ::: "memory");
    __builtin_amdgcn_s_barrier();

    int kof = 0;        // compute K-buffer offset: t%3 * 8192
    int sof = 16384;    // stage target: (t+2)%3 * 8192

    for (int t = 0; t < NT; ++t) {
        // ---- V(t) fragments: 8 coalesced dwordx4 from L2 into regs (issued first!) ----
        const unsigned short* vbt = vbh + (size_t)t * 4096;
        u32x4 va[8];
#pragma unroll
        for (int i = 0; i < 8; ++i)
            va[i] = *(const u32x4*)(vbt + i * 512 + lane * 8);

        // ---- stage K(t+2) (after V loads, so the pre-PV wait keeps these in flight) ----
        if (t + 2 < NT) STAGE_K(sof, t + 2);

        // ---- QK(t): S^T = K * Q (K(t) ready via prev iter's wait + barrier) ----
        f32x16 sa = (f32x16)0.f;
        __builtin_amdgcn_s_setprio(1);
#pragma unroll
        for (int s = 0; s < 8; ++s) {
            bf16x8 kf = *(const bf16x8*)&smemc[kad[s] + kof];
            sa = __builtin_amdgcn_mfma_f32_32x32x16_bf16(kf, qf[s], sa, 0, 0, 0);
        }
        __builtin_amdgcn_s_setprio(0);

        // ---- in-register online softmax (log2 domain) ----
        {
            float t0 = fmaxf(fmaxf(sa[0], sa[1]),   fmaxf(sa[2], sa[3]));
            float t1 = fmaxf(fmaxf(sa[4], sa[5]),   fmaxf(sa[6], sa[7]));
            float t2 = fmaxf(fmaxf(sa[8], sa[9]),   fmaxf(sa[10], sa[11]));
            float t3 = fmaxf(fmaxf(sa[12], sa[13]), fmaxf(sa[14], sa[15]));
            float tm = fmaxf(fmaxf(t0, t1), fmaxf(t2, t3));
            tm = fmaxf(tm, __shfl_xor(tm, 32));
            if (!__all(tm <= mr + THRL2)) {           // defer-max (T13)
                float mn   = fmaxf(mr, tm);
                float corr = ex2(mr - mn);
                lsum *= corr;
#pragma unroll
                for (int db = 0; db < 4; ++db)
#pragma unroll
                    for (int r = 0; r < 16; ++r) acc[db][r] *= corr;
                mr = mn;
            }
#pragma unroll
            for (int r = 0; r < 16; ++r) sa[r] = ex2(sa[r] - mr);
            float s0 = (sa[0] + sa[1]) + (sa[2] + sa[3]);
            float s1 = (sa[4] + sa[5]) + (sa[6] + sa[7]);
            float s2 = (sa[8] + sa[9]) + (sa[10] + sa[11]);
            float s3 = (sa[12] + sa[13]) + (sa[14] + sa[15]);
            lsum += (s0 + s1) + (s2 + s3);            // cross-h shfl deferred to epilogue
        }

        // ---- P -> bf16 PV fragments ----
        bf16x8 pa[2];
        pa[0] = make_pa<0>(sa);
        pa[1] = make_pa<8>(sa);

        // ---- PV(t): O^T += V^T * P^T ; compiler waits for va here (retires K(t+1) too) ----
        __builtin_amdgcn_s_setprio(1);
#pragma unroll
        for (int db = 0; db < 4; ++db) {
#pragma unroll
            for (int ks = 0; ks < 2; ++ks) {
                bf16x8 vf = __builtin_bit_cast(bf16x8, va[ks * 4 + db]);
                acc[db] = __builtin_amdgcn_mfma_f32_32x32x16_bf16(vf, pa[ks], acc[db], 0, 0, 0);
            }
        }
        __builtin_amdgcn_s_setprio(0);

        // K(t+1) is already retired (it was issued before V(t)); raw arrival barrier only
        __builtin_amdgcn_s_barrier();

        kof = (kof == 16384) ? 0 : kof + 8192;
        sof = (sof == 16384) ? 0 : sof + 8192;
    }
#undef STAGE_K

    // ---- epilogue: final lsum reduce, normalize, LDS transpose, coalesced stores ----
    __syncthreads();   // all waves done reading K LDS
    lsum += __shfl_xor(lsum, 32);
    float invl = 1.f / lsum;
    float* ep = (float*)(void*)smemc + w * 2176;   // 32 x 68 f32 per wave
    const int qtb = qtile * QTILE + w * QW;
    float* ob = O + b * (NHQ * HD) + hq * HD;

#pragma unroll
    for (int pass = 0; pass < 2; ++pass) {
#pragma unroll
        for (int db2 = 0; db2 < 2; ++db2) {
            const int db = pass * 2 + db2;
#pragma unroll
            for (int r = 0; r < 16; ++r)
                ep[q31 * 68 + db2 * 32 + (r & 3) + 8 * (r >> 2) + 4 * h] = acc[db][r] * invl;
        }
        __syncthreads();
#pragma unroll
        for (int i = 0; i < 8; ++i) {
            const int row = i * 4 + (lane >> 4);
            const int f4  = lane & 15;
            float4 val = *(const float4*)&ep[row * 68 + f4 * 4];
            *(float4*)(ob + (size_t)(qtb + row) * QSTRIDE + pass * 64 + f4 * 4) = val;
        }
        __syncthreads();
    }
}

// ---------------- fallback (round-1 kernel, used if ws too small) ----------------
#define KPAD  136
#define VPAD  72
#define PPAD  72
__global__ __launch_bounds__(512, 2)
void attn_fwd(const float* __restrict__ Q, const float* __restrict__ K,
              const float* __restrict__ V, float* __restrict__ O) {
    __shared__ __align__(16) unsigned short kbuf[64 * KPAD];
    __shared__ __align__(16) unsigned short vbuf[HD * VPAD];
    __shared__ __align__(16) unsigned short pbuf[8][16 * PPAD];

    const int tid = threadIdx.x;
    const int w = tid >> 6, lane = tid & 63;
    const int row16 = lane & 15, kg = lane >> 4;
    const int bid = blockIdx.x;
    const int qtile = bid & 7, g = (bid >> 3) & 3, b = (bid >> 5) & 1, hkv = bid >> 6;
    const int hq = hkv * 4 + g;
    const int qbase = qtile * 256 + w * 32;

    ushort8 qf[2][4];
#pragma unroll
    for (int s = 0; s < 2; ++s) {
        const int qrow = qbase + s * 16 + row16;
        const float* qp = Q + (size_t)qrow * QSTRIDE + b * (NHQ * HD) + hq * HD;
#pragma unroll
        for (int kk = 0; kk < 4; ++kk) {
            const float* p = qp + kk * 32 + kg * 8;
            float4 f0 = *(const float4*)(p);
            float4 f1 = *(const float4*)(p + 4);
            ushort8 u;
            u[0] = f2bf(f0.x * SCALE); u[1] = f2bf(f0.y * SCALE);
            u[2] = f2bf(f0.z * SCALE); u[3] = f2bf(f0.w * SCALE);
            u[4] = f2bf(f1.x * SCALE); u[5] = f2bf(f1.y * SCALE);
            u[6] = f2bf(f1.z * SCALE); u[7] = f2bf(f1.w * SCALE);
            qf[s][kk] = u;
        }
    }
    float m[2][4], lsum[2][4];
    f32x4 acco[2][8];
#pragma unroll
    for (int s = 0; s < 2; ++s)
#pragma unroll
        for (int r = 0; r < 4; ++r) { m[s][r] = -1e30f; lsum[s][r] = 0.f; }
#pragma unroll
    for (int s = 0; s < 2; ++s)
#pragma unroll
        for (int n = 0; n < 8; ++n) acco[s][n] = (f32x4)0.f;

    const float* kb0 = K + b * (NHKV * HD) + hkv * HD;
    const float* vb0 = V + b * (NHKV * HD) + hkv * HD;

    for (int kvt = 0; kvt < SEQ / 64; ++kvt) {
        const int kv0 = kvt * 64;
        __syncthreads();
        const float* kb = kb0 + (size_t)kv0 * KSTRIDE;
#pragma unroll
        for (int i = 0; i < 2; ++i) {
            int c = i * 512 + tid;
            int row = c >> 4, c8 = c & 15;
            const float* src = kb + (size_t)row * KSTRIDE + c8 * 8;
            float4 f0 = *(const float4*)(src);
            float4 f1 = *(const float4*)(src + 4);
            ushort8 u;
            u[0] = f2bf(f0.x); u[1] = f2bf(f0.y); u[2] = f2bf(f0.z); u[3] = f2bf(f0.w);
            u[4] = f2bf(f1.x); u[5] = f2bf(f1.y); u[6] = f2bf(f1.z); u[7] = f2bf(f1.w);
            *(ushort8*)&kbuf[row * KPAD + c8 * 8] = u;
        }
        const float* vb = vb0 + (size_t)kv0 * KSTRIDE;
#pragma unroll
        for (int i = 0; i < 4; ++i) {
            int f4i = i * 512 + tid;
            int kv = f4i >> 5, d0 = (f4i & 31) * 4;
            float4 v4 = *(const float4*)(vb + (size_t)kv * KSTRIDE + d0);
            vbuf[(d0 + 0) * VPAD + kv] = f2bf(v4.x);
            vbuf[(d0 + 1) * VPAD + kv] = f2bf(v4.y);
            vbuf[(d0 + 2) * VPAD + kv] = f2bf(v4.z);
            vbuf[(d0 + 3) * VPAD + kv] = f2bf(v4.w);
        }
        __syncthreads();

        f32x4 sa[2][4];
#pragma unroll
        for (int s = 0; s < 2; ++s)
#pragma unroll
            for (int n = 0; n < 4; ++n) sa[s][n] = (f32x4)0.f;
#pragma unroll
        for (int kk = 0; kk < 4; ++kk) {
#pragma unroll
            for (int n = 0; n < 4; ++n) {
                bf16x8 bfr = *(const bf16x8*)&kbuf[(n * 16 + row16) * KPAD + kk * 32 + kg * 8];
                sa[0][n] = __builtin_amdgcn_mfma_f32_16x16x32_bf16(
                    __builtin_bit_cast(bf16x8, qf[0][kk]), bfr, sa[0][n], 0, 0, 0);
                sa[1][n] = __builtin_amdgcn_mfma_f32_16x16x32_bf16(
                    __builtin_bit_cast(bf16x8, qf[1][kk]), bfr, sa[1][n], 0, 0, 0);
            }
        }
#pragma unroll
        for (int s = 0; s < 2; ++s) {
#pragma unroll
            for (int r = 0; r < 4; ++r) {
                float tm = fmaxf(fmaxf(sa[s][0][r], sa[s][1][r]), fmaxf(sa[s][2][r], sa[s][3][r]));
                tm = fmaxf(tm, __shfl_xor(tm, 1, 16));
                tm = fmaxf(tm, __shfl_xor(tm, 2, 16));
                tm = fmaxf(tm, __shfl_xor(tm, 4, 16));
                tm = fmaxf(tm, __shfl_xor(tm, 8, 16));
                float mn = fmaxf(m[s][r], tm);
                float corr = __expf(m[s][r] - mn);
                float ps = 0.f;
                int prow = kg * 4 + r;
#pragma unroll
                for (int n = 0; n < 4; ++n) {
                    float p = __expf(sa[s][n][r] - mn);
                    ps += p;
                    pbuf[w][prow * PPAD + n * 16 + row16] = f2bf(p);
                }
                ps += __shfl_xor(ps, 1, 16);
                ps += __shfl_xor(ps, 2, 16);
                ps += __shfl_xor(ps, 4, 16);
                ps += __shfl_xor(ps, 8, 16);
                lsum[s][r] = lsum[s][r] * corr + ps;
                m[s][r] = mn;
#pragma unroll
                for (int n8 = 0; n8 < 8; ++n8) acco[s][n8][r] *= corr;
            }
#pragma unroll
            for (int kk2 = 0; kk2 < 2; ++kk2) {
                bf16x8 pa = *(const bf16x8*)&pbuf[w][row16 * PPAD + kk2 * 32 + kg * 8];
#pragma unroll
                for (int n8 = 0; n8 < 8; ++n8) {
                    bf16x8 vf = *(const bf16x8*)&vbuf[(n8 * 16 + row16) * VPAD + kk2 * 32 + kg * 8];
                    acco[s][n8] = __builtin_amdgcn_mfma_f32_16x16x32_bf16(pa, vf, acco[s][n8], 0, 0, 0);
                }
            }
        }
    }
    float* ob = O + b * (NHQ * HD) + hq * HD;
#pragma unroll
    for (int s = 0; s < 2; ++s)
#pragma unroll
        for (int r = 0; r < 4; ++r) {
            float inv = 1.f / lsum[s][r];
            int qrow = qbase + s * 16 + kg * 4 + r;
            float* op = ob + (size_t)qrow * QSTRIDE;
#pragma unroll
            for (int n8 = 0; n8 < 8; ++n8)
                op[n8 * 16 + row16] = acco[s][n8][r] * inv;
        }
}

extern "C" void kernel_launch(void* const* d_in, const int* in_sizes, int n_in,
                              void* d_out, int out_size, void* d_ws, size_t ws_size,
                              hipStream_t stream) {
    (void)in_sizes; (void)n_in; (void)out_size;
    const float* Q = (const float*)d_in[0];
    const float* K = (const float*)d_in[1];
    const float* V = (const float*)d_in[2];
    float* Out = (float*)d_out;

    const size_t kv_elems = (size_t)16 * 2048 * 128;
    const size_t need = kv_elems * 2 * sizeof(unsigned short);

    if (ws_size >= need) {
        unsigned short* Kws = (unsigned short*)d_ws;
        unsigned short* Vt2 = Kws + kv_elems;
        conv_k<<<dim3(2048), dim3(256), 0, stream>>>(K, Kws);
        conv_v<<<dim3(512), dim3(256), 0, stream>>>(V, Vt2);
        attn_fwd9<<<dim3(1024), dim3(256), 0, stream>>>(Q, Kws, Vt2, Out);
    } else {
        attn_fwd<<<dim3(512), dim3(512), 0, stream>>>(Q, K, V, Out);
    }
}

// Round 11
// 174.666 us; speedup vs baseline: 1.3876x; 1.3876x over previous
//
#include <hip/hip_runtime.h>

// Shapes (fixed)
#define SEQ   2048
#define NB    2
#define NHQ   32
#define NHKV  8
#define HD    128
#define QTILE 128      // q rows per block (4 waves x 32 q)
#define QW    32
#define KVB   32
#define NT    (SEQ / KVB)    // 64 kv tiles
#define SCALE 0.08838834764831845f
#define QSCALE (0.08838834764831845f * 1.4426950408889634f)   // fold log2(e): use exp2
#define THRL2 11.5f

#define QSTRIDE (NB * NHQ * HD)    // 8192
#define KSTRIDE (NB * NHKV * HD)   // 2048

typedef float f32x4  __attribute__((ext_vector_type(4)));
typedef float f32x16 __attribute__((ext_vector_type(16)));
typedef __bf16 bf16x8 __attribute__((ext_vector_type(8)));
typedef unsigned short ushort8 __attribute__((ext_vector_type(8)));
typedef unsigned int u32;
typedef unsigned int u32x2 __attribute__((ext_vector_type(2)));
typedef unsigned int u32x4 __attribute__((ext_vector_type(4)));

__device__ __forceinline__ unsigned short f2bf(float f) {
    union { float f; unsigned u; } c; c.f = f;
    return (unsigned short)((c.u + 0x7fffu + ((c.u >> 16) & 1u)) >> 16);
}

__device__ __forceinline__ void gload_lds16(const unsigned short* g, unsigned short* l) {
    __builtin_amdgcn_global_load_lds((const __attribute__((address_space(1))) u32*)g,
                                     (__attribute__((address_space(3))) u32*)l, 16, 0, 0);
}

__device__ __forceinline__ float ex2(float x) {
#if __has_builtin(__builtin_amdgcn_exp2f)
    return __builtin_amdgcn_exp2f(x);
#else
    return exp2f(x);
#endif
}

__device__ __forceinline__ u32 cvtpk(float lo, float hi) {
    u32 r;
    asm("v_cvt_pk_bf16_f32 %0, %1, %2" : "=v"(r) : "v"(lo), "v"(hi));
    return r;
}

// v_permlane32_swap_b32 a, b : swaps a's UPPER 32 lanes with b's LOWER 32 lanes
__device__ __forceinline__ void pl32swap(u32& a, u32& b) {
#if __has_builtin(__builtin_amdgcn_permlane32_swap)
    u32x2 r = __builtin_amdgcn_permlane32_swap(a, b, false, false);
    a = r.x; b = r.y;
#else
    asm("v_permlane32_swap_b32 %0, %1" : "+v"(a), "+v"(b));
#endif
}

// Pack 8 f32 P values (C-layout rows r=B..B+7) into one PV B-fragment:
// pa elem j = P[8h + j] of the 16-kv slice. Verified R4.
template <int B>
__device__ __forceinline__ bf16x8 make_pa(const f32x16 p) {
    u32 w0 = cvtpk(p[B + 0], p[B + 1]);
    u32 w2 = cvtpk(p[B + 4], p[B + 5]);
    pl32swap(w0, w2);
    u32 w1 = cvtpk(p[B + 2], p[B + 3]);
    u32 w3 = cvtpk(p[B + 6], p[B + 7]);
    pl32swap(w1, w3);
    u32x4 v = {w0, w1, w2, w3};
    return __builtin_bit_cast(bf16x8, v);
}

// ---- pre-pass 1: K -> bf16 fragment-major: Kf[bh][t32][chunk c 0..15][row r 0..31] (16B units)
// unit value j = K[t*32+r][bh][c*8+j]. One block per (bh,t).
__global__ __launch_bounds__(256) void conv_k(const float* __restrict__ K,
                                              unsigned short* __restrict__ Kf) {
    __shared__ float tile[32][129];
    int t  = blockIdx.x & 63;
    int bh = blockIdx.x >> 6;
#pragma unroll
    for (int i = 0; i < 4; ++i) {
        int f4 = i * 256 + threadIdx.x;        // 0..1023 float4s
        int r = f4 >> 5, d4 = (f4 & 31) * 4;
        float4 v = *(const float4*)(K + ((size_t)(t * 32 + r) * 16 + bh) * 128 + d4);
        tile[r][d4] = v.x; tile[r][d4 + 1] = v.y;
        tile[r][d4 + 2] = v.z; tile[r][d4 + 3] = v.w;
    }
    __syncthreads();
#pragma unroll
    for (int i = 0; i < 2; ++i) {
        int lin = i * 256 + threadIdx.x;       // 0..511 = c(16) x r(32)
        int r = lin & 31, c = lin >> 5;
        ushort8 u;
#pragma unroll
        for (int j = 0; j < 8; ++j) u[j] = f2bf(tile[r][c * 8 + j]);
        *(ushort8*)&Kf[((size_t)(bh * 64 + t) * 16 + c) * 256 + r * 8] = u;
    }
}

// ---- pre-pass 2: V -> bf16 fragment-major: Vf[bh][t32][cv 0..3][db 0..3][row r 0..31]
// unit value j = V[t*32 + cv*8 + j][bh][db*32 + r]. One block per (bh,t).
__global__ __launch_bounds__(256) void conv_v(const float* __restrict__ V,
                                              unsigned short* __restrict__ Vf) {
    __shared__ float tile[32][129];
    int t  = blockIdx.x & 63;
    int bh = blockIdx.x >> 6;
#pragma unroll
    for (int i = 0; i < 4; ++i) {
        int f4 = i * 256 + threadIdx.x;
        int kv = f4 >> 5, d4 = (f4 & 31) * 4;
        float4 v = *(const float4*)(V + ((size_t)(t * 32 + kv) * 16 + bh) * 128 + d4);
        tile[kv][d4] = v.x; tile[kv][d4 + 1] = v.y;
        tile[kv][d4 + 2] = v.z; tile[kv][d4 + 3] = v.w;
    }
    __syncthreads();
#pragma unroll
    for (int i = 0; i < 2; ++i) {
        int lin = i * 256 + threadIdx.x;       // 0..511 = cv(4) x db(4) x r(32)
        int r = lin & 31, db = (lin >> 5) & 3, cv = lin >> 7;
        ushort8 u;
#pragma unroll
        for (int j = 0; j < 8; ++j) u[j] = f2bf(tile[cv * 8 + j][db * 32 + r]);
        *(ushort8*)&Vf[((size_t)(bh * 64 + t) * 16 + cv * 4 + db) * 256 + r * 8] = u;
    }
}

// -------- main kernel: 4 waves x 32q, KVB=32; fragment-major LDS, tri-buffer, vmcnt(4) --------
// K region: [0, 24576) = 3 x 8 KB ; V region: [24576, 49152) = 3 x 8 KB
// epilogue reuses [0, 34816): 4 waves x 32x68 f32
__global__ __launch_bounds__(256, 3)
void attn_fwd10(const float* __restrict__ Q, const unsigned short* __restrict__ Kf,
                const unsigned short* __restrict__ Vf, float* __restrict__ O) {
    __shared__ __align__(16) unsigned char smemc[49152];

    const int tid  = threadIdx.x;
    const int w    = tid >> 6;     // 0..3
    const int lane = tid & 63;
    const int q31  = lane & 31;
    const int h    = lane >> 5;

    // XCD-locality decode: hkv = bid&7
    const int bid   = blockIdx.x;
    const int hkv   = bid & 7;
    const int rest  = bid >> 3;
    const int g     = rest & 3;
    const int b     = (rest >> 2) & 1;
    const int qtile = rest >> 3;          // 0..15
    const int hq    = hkv * 4 + g;

    const int qrow = qtile * QTILE + w * QW + q31;

    // ---- Q B-fragments: qf[s] elem j = Q[qrow][16s+8h+j] * QSCALE ----
    bf16x8 qf[8];
    {
        const float* qp = Q + (size_t)qrow * QSTRIDE + b * (NHQ * HD) + hq * HD;
#pragma unroll
        for (int s = 0; s < 8; ++s) {
            const float* p = qp + (2 * s + h) * 8;
            float4 f0 = *(const float4*)(p);
            float4 f1 = *(const float4*)(p + 4);
            ushort8 u;
            u[0] = f2bf(f0.x * QSCALE); u[1] = f2bf(f0.y * QSCALE);
            u[2] = f2bf(f0.z * QSCALE); u[3] = f2bf(f0.w * QSCALE);
            u[4] = f2bf(f1.x * QSCALE); u[5] = f2bf(f1.y * QSCALE);
            u[6] = f2bf(f1.z * QSCALE); u[7] = f2bf(f1.w * QSCALE);
            qf[s] = __builtin_bit_cast(bf16x8, u);
        }
    }

    // fragment-major per-lane bases (stride-1 across lanes => conflict-free)
    const u32 kbase = h * 512 + q31 * 16;                 // + s*1024 + kof
    const u32 vbase = 24576 + h * 2048 + q31 * 16;        // + ks*4096 + db*512 + kof

    f32x16 acc[4];
#pragma unroll
    for (int db = 0; db < 4; ++db) acc[db] = (f32x16)0.f;
    float mr = -3e38f, lsum = 0.f;

    const unsigned short* kbh = Kf + (size_t)(b * 8 + hkv) * 2048 * 128;
    const unsigned short* vbh = Vf + (size_t)(b * 8 + hkv) * 2048 * 128;

    // identity-mapped staging: per wave 2x 1KB for K and V (4 vmem insts)
#define STAGE(sofb, tt) do {                                                           \
        _Pragma("unroll")                                                              \
        for (int i_ = 0; i_ < 2; ++i_) {                                               \
            const int c_ = w * 2 + i_;                                                 \
            gload_lds16(kbh + (size_t)(tt) * 4096 + c_ * 512 + lane * 8,               \
                        (unsigned short*)(smemc + (sofb) + c_ * 1024));                \
            gload_lds16(vbh + (size_t)(tt) * 4096 + c_ * 512 + lane * 8,               \
                        (unsigned short*)(smemc + 24576 + (sofb) + c_ * 1024));        \
        }                                                                              \
    } while (0)

    STAGE(0, 0);
    STAGE(8192, 1);
    int kof = 0;        // compute-buffer offset: t%3 * 8192
    int sof = 16384;    // stage target: (t+2)%3 * 8192

    for (int t = 0; t < NT; ++t) {
        // tile t's 4 loads issued 2 tiles ago; keep tile t+1's 4 in flight
        if (t < NT - 1) {
            asm volatile("s_waitcnt vmcnt(4)" ::: "memory");
        } else {
            asm volatile("s_waitcnt vmcnt(0)" ::: "memory");
        }
        __builtin_amdgcn_s_barrier();
        if (t + 2 < NT) STAGE(sof, t + 2);

        // ---- QK(t): S^T = K * Q ----
        f32x16 sa = (f32x16)0.f;
        __builtin_amdgcn_s_setprio(1);
#pragma unroll
        for (int s = 0; s < 8; ++s) {
            bf16x8 kf = *(const bf16x8*)&smemc[kbase + s * 1024 + kof];
            sa = __builtin_amdgcn_mfma_f32_32x32x16_bf16(kf, qf[s], sa, 0, 0, 0);
        }
        __builtin_amdgcn_s_setprio(0);

        // ---- in-register online softmax (log2 domain) ----
        {
            float t0 = fmaxf(fmaxf(sa[0], sa[1]),   fmaxf(sa[2], sa[3]));
            float t1 = fmaxf(fmaxf(sa[4], sa[5]),   fmaxf(sa[6], sa[7]));
            float t2 = fmaxf(fmaxf(sa[8], sa[9]),   fmaxf(sa[10], sa[11]));
            float t3 = fmaxf(fmaxf(sa[12], sa[13]), fmaxf(sa[14], sa[15]));
            float tm = fmaxf(fmaxf(t0, t1), fmaxf(t2, t3));
            tm = fmaxf(tm, __shfl_xor(tm, 32));
            if (!__all(tm <= mr + THRL2)) {           // defer-max (T13)
                float mn   = fmaxf(mr, tm);
                float corr = ex2(mr - mn);
                lsum *= corr;
#pragma unroll
                for (int db = 0; db < 4; ++db)
#pragma unroll
                    for (int r = 0; r < 16; ++r) acc[db][r] *= corr;
                mr = mn;
            }
#pragma unroll
            for (int r = 0; r < 16; ++r) sa[r] = ex2(sa[r] - mr);
            float s0 = (sa[0] + sa[1]) + (sa[2] + sa[3]);
            float s1 = (sa[4] + sa[5]) + (sa[6] + sa[7]);
            float s2 = (sa[8] + sa[9]) + (sa[10] + sa[11]);
            float s3 = (sa[12] + sa[13]) + (sa[14] + sa[15]);
            lsum += (s0 + s1) + (s2 + s3);            // cross-h shfl deferred to epilogue
        }

        // ---- P -> bf16 PV fragments ----
        bf16x8 pa[2];
        pa[0] = make_pa<0>(sa);
        pa[1] = make_pa<8>(sa);

        // ---- PV(t): O^T += V^T * P^T ----
        __builtin_amdgcn_s_setprio(1);
#pragma unroll
        for (int db = 0; db < 4; ++db) {
#pragma unroll
            for (int ks = 0; ks < 2; ++ks) {
                bf16x8 vf = *(const bf16x8*)&smemc[vbase + ks * 4096 + db * 512 + kof];
                acc[db] = __builtin_amdgcn_mfma_f32_32x32x16_bf16(vf, pa[ks], acc[db], 0, 0, 0);
            }
        }
        __builtin_amdgcn_s_setprio(0);

        kof = (kof == 16384) ? 0 : kof + 8192;
        sof = (sof == 16384) ? 0 : sof + 8192;
    }
#undef STAGE

    // ---- epilogue: final lsum reduce, normalize, LDS transpose, coalesced stores ----
    __syncthreads();   // all waves done reading K/V LDS
    lsum += __shfl_xor(lsum, 32);
    float invl = 1.f / lsum;
    float* ep = (float*)(void*)smemc + w * 2176;   // 32 x 68 f32 per wave
    const int qtb = qtile * QTILE + w * QW;
    float* ob = O + b * (NHQ * HD) + hq * HD;

#pragma unroll
    for (int pass = 0; pass < 2; ++pass) {
#pragma unroll
        for (int db2 = 0; db2 < 2; ++db2) {
            const int db = pass * 2 + db2;
#pragma unroll
            for (int r = 0; r < 16; ++r)
                ep[q31 * 68 + db2 * 32 + (r & 3) + 8 * (r >> 2) + 4 * h] = acc[db][r] * invl;
        }
        __syncthreads();
#pragma unroll
        for (int i = 0; i < 8; ++i) {
            const int row = i * 4 + (lane >> 4);
            const int f4  = lane & 15;
            float4 val = *(const float4*)&ep[row * 68 + f4 * 4];
            *(float4*)(ob + (size_t)(qtb + row) * QSTRIDE + pass * 64 + f4 * 4) = val;
        }
        __syncthreads();
    }
}

// ---------------- fallback (round-1 kernel, used if ws too small) ----------------
#define KPAD  136
#define VPAD  72
#define PPAD  72
__global__ __launch_bounds__(512, 2)
void attn_fwd(const float* __restrict__ Q, const float* __restrict__ K,
              const float* __restrict__ V, float* __restrict__ O) {
    __shared__ __align__(16) unsigned short kbuf[64 * KPAD];
    __shared__ __align__(16) unsigned short vbuf[HD * VPAD];
    __shared__ __align__(16) unsigned short pbuf[8][16 * PPAD];

    const int tid = threadIdx.x;
    const int w = tid >> 6, lane = tid & 63;
    const int row16 = lane & 15, kg = lane >> 4;
    const int bid = blockIdx.x;
    const int qtile = bid & 7, g = (bid >> 3) & 3, b = (bid >> 5) & 1, hkv = bid >> 6;
    const int hq = hkv * 4 + g;
    const int qbase = qtile * 256 + w * 32;

    ushort8 qf[2][4];
#pragma unroll
    for (int s = 0; s < 2; ++s) {
        const int qrow = qbase + s * 16 + row16;
        const float* qp = Q + (size_t)qrow * QSTRIDE + b * (NHQ * HD) + hq * HD;
#pragma unroll
        for (int kk = 0; kk < 4; ++kk) {
            const float* p = qp + kk * 32 + kg * 8;
            float4 f0 = *(const float4*)(p);
            float4 f1 = *(const float4*)(p + 4);
            ushort8 u;
            u[0] = f2bf(f0.x * SCALE); u[1] = f2bf(f0.y * SCALE);
            u[2] = f2bf(f0.z * SCALE); u[3] = f2bf(f0.w * SCALE);
            u[4] = f2bf(f1.x * SCALE); u[5] = f2bf(f1.y * SCALE);
            u[6] = f2bf(f1.z * SCALE); u[7] = f2bf(f1.w * SCALE);
            qf[s][kk] = u;
        }
    }
    float m[2][4], lsum[2][4];
    f32x4 acco[2][8];
#pragma unroll
    for (int s = 0; s < 2; ++s)
#pragma unroll
        for (int r = 0; r < 4; ++r) { m[s][r] = -1e30f; lsum[s][r] = 0.f; }
#pragma unroll
    for (int s = 0; s < 2; ++s)
#pragma unroll
        for (int n = 0; n < 8; ++n) acco[s][n] = (f32x4)0.f;

    const float* kb0 = K + b * (NHKV * HD) + hkv * HD;
    const float* vb0 = V + b * (NHKV * HD) + hkv * HD;

    for (int kvt = 0; kvt < SEQ / 64; ++kvt) {
        const int kv0 = kvt * 64;
        __syncthreads();
        const float* kb = kb0 + (size_t)kv0 * KSTRIDE;
#pragma unroll
        for (int i = 0; i < 2; ++i) {
            int c = i * 512 + tid;
            int row = c >> 4, c8 = c & 15;
            const float* src = kb + (size_t)row * KSTRIDE + c8 * 8;
            float4 f0 = *(const float4*)(src);
            float4 f1 = *(const float4*)(src + 4);
            ushort8 u;
            u[0] = f2bf(f0.x); u[1] = f2bf(f0.y); u[2] = f2bf(f0.z); u[3] = f2bf(f0.w);
            u[4] = f2bf(f1.x); u[5] = f2bf(f1.y); u[6] = f2bf(f1.z); u[7] = f2bf(f1.w);
            *(ushort8*)&kbuf[row * KPAD + c8 * 8] = u;
        }
        const float* vb = vb0 + (size_t)kv0 * KSTRIDE;
#pragma unroll
        for (int i = 0; i < 4; ++i) {
            int f4i = i * 512 + tid;
            int kv = f4i >> 5, d0 = (f4i & 31) * 4;
            float4 v4 = *(const float4*)(vb + (size_t)kv * KSTRIDE + d0);
            vbuf[(d0 + 0) * VPAD + kv] = f2bf(v4.x);
            vbuf[(d0 + 1) * VPAD + kv] = f2bf(v4.y);
            vbuf[(d0 + 2) * VPAD + kv] = f2bf(v4.z);
            vbuf[(d0 + 3) * VPAD + kv] = f2bf(v4.w);
        }
        __syncthreads();

        f32x4 sa[2][4];
#pragma unroll
        for (int s = 0; s < 2; ++s)
#pragma unroll
            for (int n = 0; n < 4; ++n) sa[s][n] = (f32x4)0.f;
#pragma unroll
        for (int kk = 0; kk < 4; ++kk) {
#pragma unroll
            for (int n = 0; n < 4; ++n) {
                bf16x8 bfr = *(const bf16x8*)&kbuf[(n * 16 + row16) * KPAD + kk * 32 + kg * 8];
                sa[0][n] = __builtin_amdgcn_mfma_f32_16x16x32_bf16(
                    __builtin_bit_cast(bf16x8, qf[0][kk]), bfr, sa[0][n], 0, 0, 0);
                sa[1][n] = __builtin_amdgcn_mfma_f32_16x16x32_bf16(
                    __builtin_bit_cast(bf16x8, qf[1][kk]), bfr, sa[1][n], 0, 0, 0);
            }
        }
#pragma unroll
        for (int s = 0; s < 2; ++s) {
#pragma unroll
            for (int r = 0; r < 4; ++r) {
                float tm = fmaxf(fmaxf(sa[s][0][r], sa[s][1][r]), fmaxf(sa[s][2][r], sa[s][3][r]));
                tm = fmaxf(tm, __shfl_xor(tm, 1, 16));
                tm = fmaxf(tm, __shfl_xor(tm, 2, 16));
                tm = fmaxf(tm, __shfl_xor(tm, 4, 16));
                tm = fmaxf(tm, __shfl_xor(tm, 8, 16));
                float mn = fmaxf(m[s][r], tm);
                float corr = __expf(m[s][r] - mn);
                float ps = 0.f;
                int prow = kg * 4 + r;
#pragma unroll
                for (int n = 0; n < 4; ++n) {
                    float p = __expf(sa[s][n][r] - mn);
                    ps += p;
                    pbuf[w][prow * PPAD + n * 16 + row16] = f2bf(p);
                }
                ps += __shfl_xor(ps, 1, 16);
                ps += __shfl_xor(ps, 2, 16);
                ps += __shfl_xor(ps, 4, 16);
                ps += __shfl_xor(ps, 8, 16);
                lsum[s][r] = lsum[s][r] * corr + ps;
                m[s][r] = mn;
#pragma unroll
                for (int n8 = 0; n8 < 8; ++n8) acco[s][n8][r] *= corr;
            }
#pragma unroll
            for (int kk2 = 0; kk2 < 2; ++kk2) {
                bf16x8 pa = *(const bf16x8*)&pbuf[w][row16 * PPAD + kk2 * 32 + kg * 8];
#pragma unroll
                for (int n8 = 0; n8 < 8; ++n8) {
                    bf16x8 vf = *(const bf16x8*)&vbuf[(n8 * 16 + row16) * VPAD + kk2 * 32 + kg * 8];
                    acco[s][n8] = __builtin_amdgcn_mfma_f32_16x16x32_bf16(pa, vf, acco[s][n8], 0, 0, 0);
                }
            }
        }
    }
    float* ob = O + b * (NHQ * HD) + hq * HD;
#pragma unroll
    for (int s = 0; s < 2; ++s)
#pragma unroll
        for (int r = 0; r < 4; ++r) {
            float inv = 1.f / lsum[s][r];
            int qrow = qbase + s * 16 + kg * 4 + r;
            float* op = ob + (size_t)qrow * QSTRIDE;
#pragma unroll
            for (int n8 = 0; n8 < 8; ++n8)
                op[n8 * 16 + row16] = acco[s][n8][r] * inv;
        }
}

extern "C" void kernel_launch(void* const* d_in, const int* in_sizes, int n_in,
                              void* d_out, int out_size, void* d_ws, size_t ws_size,
                              hipStream_t stream) {
    (void)in_sizes; (void)n_in; (void)out_size;
    const float* Q = (const float*)d_in[0];
    const float* K = (const float*)d_in[1];
    const float* V = (const float*)d_in[2];
    float* Out = (float*)d_out;

    const size_t kv_elems = (size_t)16 * 2048 * 128;
    const size_t need = kv_elems * 2 * sizeof(unsigned short);

    if (ws_size >= need) {
        unsigned short* Kf = (unsigned short*)d_ws;
        unsigned short* Vf = Kf + kv_elems;
        conv_k<<<dim3(1024), dim3(256), 0, stream>>>(K, Kf);
        conv_v<<<dim3(1024), dim3(256), 0, stream>>>(V, Vf);
        attn_fwd10<<<dim3(1024), dim3(256), 0, stream>>>(Q, Kf, Vf, Out);
    } else {
        attn_fwd<<<dim3(512), dim3(512), 0, stream>>>(Q, K, V, Out);
    }
}